// Round 11
// baseline (593.105 us; speedup 1.0000x reference)
//
#include <hip/hip_runtime.h>

#define E 256
#define H 256
#define NNODES 65535
#define DEPTH 16
#define MT 8   // fallback fp32 kernel

typedef __attribute__((ext_vector_type(8))) short bf16x8;
typedef __attribute__((ext_vector_type(4))) float f32x4;

__device__ __forceinline__ float fast_sigmoid(float x) {
    return 1.0f / (1.0f + __expf(-x));
}
__device__ __forceinline__ float fast_tanh(float x) {
    return 1.0f - 2.0f / (__expf(2.0f * x) + 1.0f);
}
__device__ __forceinline__ ushort f2bf(float v) {
    union { float f; unsigned u; } x; x.f = v;
    unsigned r = (x.u + 0x7FFFu + ((x.u >> 16) & 1u)) >> 16;
    return (ushort)r;
}
__device__ __forceinline__ float bf2f(ushort h) {
    union { unsigned u; float f; } x; x.u = ((unsigned)h) << 16;
    return x.f;
}

// ============================================================================
// pack_B: logical B (768 x 1280) -> frag-linear bf16 Bp[kt(24)][ct(80)][64][8].
// Logical col c = g*256 + q  (g: 0=i 1=o 2=u 3=f0 4=f1);  ct = g*16 + q/16.
// Frag (kt, ct), lane l, j: value B[kt*32 + (l>>4)*8 + j][ct*16 + (l&15)].
// Rows k: 0..255 = x (Wx), 256..511 = hL, 512..767 = hR.
// ============================================================================
__global__ __launch_bounds__(256) void pack_B(const float* __restrict__ Wx,
                                              const float* __restrict__ Ui,
                                              const float* __restrict__ Uf,
                                              const float* __restrict__ Uo,
                                              const float* __restrict__ Uu,
                                              ushort* __restrict__ Bp)
{
    int tile = blockIdx.x * 4 + (threadIdx.x >> 6);   // 0..1919 = kt*80 + ct
    int l = threadIdx.x & 63;
    int kt = tile / 80;
    int ct = tile % 80;
    int g = ct >> 4;
    int q = (ct & 15) * 16 + (l & 15);
    size_t base = ((size_t)tile * 64 + l) * 8;
    #pragma unroll
    for (int j = 0; j < 8; j++) {
        int k = kt * 32 + ((l >> 4) * 8) + j;
        float v;
        if (k < 256) {
            // Wx gate order in reference: i,f,o,u
            int gc = (g == 0) ? q : (g == 1) ? (512 + q) : (g == 2) ? (768 + q) : (256 + q);
            v = Wx[(size_t)k * 1024 + gc];
        } else {
            int side = (k < 512) ? 0 : 1;            // hL / hR
            int e = k - 256 - side * 256;
            size_t off = (size_t)e * 256 + q;
            if (g == 0)      v = Ui[(size_t)side * 65536 + off];
            else if (g == 1) v = Uo[(size_t)side * 65536 + off];
            else if (g == 2) v = Uu[(size_t)side * 65536 + off];
            else {
                int j2 = g - 3;                      // forget gate of child j2
                v = Uf[(size_t)(j2 * 2 + side) * 65536 + off];
            }
        }
        Bp[base + j] = f2bf(v);
    }
}

// ============================================================================
// pack_X: X = emb[tokens] for ALL nodes -> bf16 (hi only) [node][256].
// ============================================================================
__global__ __launch_bounds__(256) void pack_X(const int* __restrict__ tokens,
                                              const float* __restrict__ emb,
                                              ushort* __restrict__ Xp)
{
    int i = blockIdx.x * 256 + threadIdx.x;           // float4 index
    if (i >= NNODES * 64) return;
    int node = i >> 6, c4 = i & 63;
    int tok = tokens[node];
    float4 v = *(const float4*)(emb + (size_t)tok * 256 + c4 * 4);
    ushort4 hv;
    hv.x = f2bf(v.x); hv.y = f2bf(v.y); hv.z = f2bf(v.z); hv.w = f2bf(v.w);
    *(ushort4*)(Xp + (size_t)node * 256 + c4 * 4) = hv;
}

// ============================================================================
// tree_direct<MTC,NG>: ALL levels, barrier-free, LDS-free.
// NG=5 internal (K=768), NG=3 leaf (K=256). Block: 256 thr (4 waves).
// Block covers MTC*16 rows x (NG x 64q) cols (nb = blockIdx.y picks 64-q blk).
// Wave w = 16-q subtile. All 4 waves read the same A frags (L1-absorbed);
// B frags are frag-linear 1KB contiguous reads (L1/L2-hot, 1.9 MB total).
// acc[MTC][NG] f32x4 per thread. Compiler pipelines the unrolled K loop.
// ============================================================================
template <int MTC, int NG>
__global__ __launch_bounds__(256) void tree_direct(
    const ushort* __restrict__ Xp, ushort* Hp,
    const float* __restrict__ bias, const ushort* __restrict__ Bp,
    float* __restrict__ hbuf, float* __restrict__ cbuf,
    float* __restrict__ rootout, int lo, int m)
{
    constexpr int KT = (NG == 3) ? 8 : 24;
    const int t = threadIdx.x;
    const int l = t & 63;
    const int w = t >> 6;
    const int base = blockIdx.x * (MTC * 16);
    const int nb = blockIdx.y;

    // per-m-tile node for A loads (lane row = l&15)
    int nodeA[MTC];
    #pragma unroll
    for (int mt = 0; mt < MTC; mt++) {
        int r = base + mt * 16 + (l & 15);
        if (r >= m) r = m - 1;
        nodeA[mt] = lo + r;
    }
    const int ksl = (l >> 4) * 8;

    f32x4 acc[MTC][NG];
    #pragma unroll
    for (int mt = 0; mt < MTC; mt++)
        #pragma unroll
        for (int g = 0; g < NG; g++)
            acc[mt][g] = (f32x4){0.f, 0.f, 0.f, 0.f};

    for (int kt = 0; kt < KT; kt++) {
        bf16x8 af[MTC];
        int k = kt * 32 + ksl;
        #pragma unroll
        for (int mt = 0; mt < MTC; mt++) {
            const ushort* s;
            if (NG == 3 || kt < 8)
                s = Xp + (size_t)nodeA[mt] * 256 + k;
            else if (kt < 16)
                s = Hp + (size_t)(2 * nodeA[mt] + 1) * 256 + (k - 256);
            else
                s = Hp + (size_t)(2 * nodeA[mt] + 2) * 256 + (k - 512);
            af[mt] = *reinterpret_cast<const bf16x8*>(s);
        }
        #pragma unroll
        for (int g = 0; g < NG; g++) {
            size_t boff = (((size_t)kt * 80 + g * 16 + nb * 4 + w) * 64 + l) * 8;
            bf16x8 bh = *reinterpret_cast<const bf16x8*>(Bp + boff);
            #pragma unroll
            for (int mt = 0; mt < MTC; mt++)
                acc[mt][g] = __builtin_amdgcn_mfma_f32_16x16x32_bf16(af[mt], bh, acc[mt][g], 0, 0, 0);
        }
    }

    // ---- LSTM epilogue: C/D col=lane&15, row=(lane>>4)*4+reg ----
    int q = nb * 64 + w * 16 + (l & 15);
    float bi = bias[q], bff = bias[256 + q], bo = bias[512 + q], bu = bias[768 + q];
    #pragma unroll
    for (int mt = 0; mt < MTC; mt++) {
        #pragma unroll
        for (int r = 0; r < 4; r++) {
            int rr = base + mt * 16 + (l >> 4) * 4 + r;
            if (rr < m) {
                int nd = lo + rr;
                float iv = fast_sigmoid(acc[mt][0][r] + bi);
                float ov = fast_sigmoid(acc[mt][1][r] + bo);
                float uv = fast_tanh(acc[mt][2][r] + bu);
                float cn;
                if constexpr (NG == 3) {
                    cn = iv * uv;
                } else {
                    float f0 = fast_sigmoid(acc[mt][3][r] + bff);
                    float f1 = fast_sigmoid(acc[mt][4][r] + bff);
                    float cl = cbuf[(size_t)(2 * nd + 1) * 256 + q];
                    float cr = cbuf[(size_t)(2 * nd + 2) * 256 + q];
                    cn = fmaf(iv, uv, fmaf(f0, cl, f1 * cr));
                }
                float hn = ov * fast_tanh(cn);
                hbuf[(size_t)nd * 256 + q] = hn;
                cbuf[(size_t)nd * 256 + q] = cn;
                Hp[(size_t)nd * 256 + q] = f2bf(hn);
                if (NG == 5 && rootout != nullptr && nd == 0) {
                    rootout[q] = hn;
                    rootout[256 + q] = cn;
                }
            }
        }
    }
}

// ============================================================================
// Last-resort fp32 path (known-correct round-2 kernel).
// ============================================================================
extern "C" __global__ void __launch_bounds__(256)
tree_level_kernel(const int* __restrict__ tokens,
                  const float* __restrict__ emb,
                  const float* __restrict__ Wx,
                  const float* __restrict__ bias,
                  const float* __restrict__ Ui,
                  const float* __restrict__ Uf,
                  const float* __restrict__ Uo,
                  const float* __restrict__ Uu,
                  float* __restrict__ hbuf,
                  float* __restrict__ cbuf,
                  float* __restrict__ rootout,
                  int lo, int m, int leaf)
{
    __shared__ float Xs[MT][E];
    __shared__ float HCs[MT][2 * H];
    const int t = threadIdx.x;
    const int base = blockIdx.x * MT;
    for (int i = t; i < MT * (E / 4); i += 256) {
        int r = i >> 6, c4 = i & 63;
        float4 v = make_float4(0.f, 0.f, 0.f, 0.f);
        if (base + r < m) {
            int node = lo + base + r;
            v = ((const float4*)(emb + (size_t)tokens[node] * E))[c4];
        }
        ((float4*)(Xs[r]))[c4] = v;
    }
    if (!leaf) {
        for (int i = t; i < MT * (2 * H / 4); i += 256) {
            int r = i >> 7, c4 = i & 127;
            float4 v = make_float4(0.f, 0.f, 0.f, 0.f);
            if (base + r < m) {
                int node = lo + base + r;
                int child = 2 * node + 1 + (c4 >> 6);
                v = ((const float4*)(hbuf + (size_t)child * H))[c4 & 63];
            }
            ((float4*)(HCs[r]))[c4] = v;
        }
    }
    __syncthreads();
    const float bi = bias[t], bf = bias[H + t], bo = bias[2 * H + t], bu = bias[3 * H + t];
    float axi[MT], axf[MT], axo[MT], axu[MT];
    #pragma unroll
    for (int r = 0; r < MT; r++) { axi[r] = bi; axf[r] = bf; axo[r] = bo; axu[r] = bu; }
    for (int e0 = 0; e0 < E; e0 += 4) {
        float4 xv[MT];
        #pragma unroll
        for (int r = 0; r < MT; r++) xv[r] = *(const float4*)&Xs[r][e0];
        #pragma unroll
        for (int q = 0; q < 4; q++) {
            const float* wrow = Wx + (size_t)(e0 + q) * (4 * H);
            float w0 = wrow[t], w1 = wrow[H + t], w2 = wrow[2 * H + t], w3 = wrow[3 * H + t];
            #pragma unroll
            for (int r = 0; r < MT; r++) {
                float xvq = ((const float*)&xv[r])[q];
                axi[r] = fmaf(xvq, w0, axi[r]);
                axf[r] = fmaf(xvq, w1, axf[r]);
                axo[r] = fmaf(xvq, w2, axo[r]);
                axu[r] = fmaf(xvq, w3, axu[r]);
            }
        }
    }
    float aci[MT], aco[MT], acu[MT], acf0[MT], acf1[MT];
    #pragma unroll
    for (int r = 0; r < MT; r++) { aci[r]=0.f; aco[r]=0.f; acu[r]=0.f; acf0[r]=0.f; acf1[r]=0.f; }
    if (!leaf) {
        for (int e0 = 0; e0 < 2 * H; e0 += 2) {
            float2 hv[MT];
            #pragma unroll
            for (int r = 0; r < MT; r++) hv[r] = *(const float2*)&HCs[r][e0];
            #pragma unroll
            for (int q = 0; q < 2; q++) {
                int e = e0 + q;
                float wi  = Ui[(size_t)e * H + t];
                float wo  = Uo[(size_t)e * H + t];
                float wu  = Uu[(size_t)e * H + t];
                float wf0 = Uf[(size_t)e * H + t];
                float wf1 = Uf[2 * H * H + (size_t)e * H + t];
                #pragma unroll
                for (int r = 0; r < MT; r++) {
                    float hvq = ((const float*)&hv[r])[q];
                    aci[r]  = fmaf(hvq, wi,  aci[r]);
                    aco[r]  = fmaf(hvq, wo,  aco[r]);
                    acu[r]  = fmaf(hvq, wu,  acu[r]);
                    acf0[r] = fmaf(hvq, wf0, acf0[r]);
                    acf1[r] = fmaf(hvq, wf1, acf1[r]);
                }
            }
        }
    }
    #pragma unroll
    for (int r = 0; r < MT; r++) {
        if (base + r < m) {
            int node = lo + base + r;
            float iv = fast_sigmoid(axi[r] + aci[r]);
            float ov = fast_sigmoid(axo[r] + aco[r]);
            float uv = fast_tanh(axu[r] + acu[r]);
            float cn;
            if (leaf) cn = iv * uv;
            else {
                float f0 = fast_sigmoid(axf[r] + acf0[r]);
                float f1 = fast_sigmoid(axf[r] + acf1[r]);
                float cl = cbuf[(size_t)(2 * node + 1) * H + t];
                float cr = cbuf[(size_t)(2 * node + 2) * H + t];
                cn = fmaf(iv, uv, fmaf(f0, cl, f1 * cr));
            }
            float hn = ov * fast_tanh(cn);
            hbuf[(size_t)node * H + t] = hn;
            cbuf[(size_t)node * H + t] = cn;
            if (rootout != nullptr && node == 0) { rootout[t] = hn; rootout[H + t] = cn; }
        }
    }
}

extern "C" void kernel_launch(void* const* d_in, const int* in_sizes, int n_in,
                              void* d_out, int out_size, void* d_ws, size_t ws_size,
                              hipStream_t stream)
{
    const int*   tokens = (const int*)d_in[0];
    const float* emb    = (const float*)d_in[1];
    const float* Wx     = (const float*)d_in[2];
    const float* bias   = (const float*)d_in[3];
    const float* Ui     = (const float*)d_in[4];
    const float* Uf     = (const float*)d_in[5];
    const float* Uo     = (const float*)d_in[6];
    const float* Uu     = (const float*)d_in[7];

    float* out = (float*)d_out;
    float* hbuf = out;                              // annotations [N, H]
    float* rootout = out + (size_t)NNODES * H;      // h[0], c[0]

    const size_t cbytes  = (size_t)NNODES * H * sizeof(float);    // 67,107,840
    const size_t bpBytes = (size_t)24 * 80 * 64 * 8 * sizeof(ushort); // 1,966,080
    const size_t packB   = (size_t)NNODES * 256 * sizeof(ushort); // 33,553,920
    const size_t need    = cbytes + bpBytes + 2 * packB;          // ~136.2 MB

    float* cbuf = (float*)d_ws;

    if (ws_size >= need) {
        ushort* Bp = (ushort*)((char*)d_ws + cbytes);
        ushort* Xp = (ushort*)((char*)d_ws + cbytes + bpBytes);
        ushort* Hp = Xp + (size_t)NNODES * 256;

        pack_B<<<480, 256, 0, stream>>>(Wx, Ui, Uf, Uo, Uu, Bp);
        pack_X<<<16384, 256, 0, stream>>>(tokens, emb, Xp);

        for (int d = DEPTH - 1; d >= 0; d--) {
            int m = 1 << d;
            int lo = m - 1;
            float* ro = (d == 0) ? rootout : nullptr;
            if (d == DEPTH - 1) {
                tree_direct<4, 3><<<dim3(m / 64, 4), 256, 0, stream>>>(
                    Xp, Hp, bias, Bp, hbuf, cbuf, nullptr, lo, m);
            } else if (m >= 64) {
                tree_direct<4, 5><<<dim3(m / 64, 4), 256, 0, stream>>>(
                    Xp, Hp, bias, Bp, hbuf, cbuf, ro, lo, m);
            } else {
                int gx = (m + 15) / 16;
                tree_direct<1, 5><<<dim3(gx, 4), 256, 0, stream>>>(
                    Xp, Hp, bias, Bp, hbuf, cbuf, ro, lo, m);
            }
        }
    } else {
        for (int d = DEPTH - 1; d >= 0; d--) {
            int m = 1 << d;
            int lo = m - 1;
            int grid = (m + MT - 1) / MT;
            tree_level_kernel<<<grid, 256, 0, stream>>>(
                tokens, emb, Wx, bias, Ui, Uf, Uo, Uu,
                hbuf, cbuf, (d == 0) ? rootout : nullptr,
                lo, m, (d == DEPTH - 1) ? 1 : 0);
        }
    }
}